// Round 12
// baseline (112.360 us; speedup 1.0000x reference)
//
#include <hip/hip_runtime.h>
#include <math.h>

// FuzzyAND: out[b,j] = max(0, 1 - sum_i sigmoid(W)[i,j] * (1 - xs[b,i]))
// B=4096, IN=1024, OUT=1024, fp32 in/out.
//
// R12: single-kernel certified-bound algorithm (R10 logic, fused).
//   s[b,j] = sum_i a_i w_i >= rowsum[b]*wmin[j]  (a_i = 1-xs[b,i] >= 0)
//   bound > 1.01 => out = 0 certified (bound ~16 at this input scale; margin
//   >> fp32 eval error). Uncertified outputs -> exact fp32 fallback (correct
//   for ALL inputs; xs>1 poisons rowsum to NaN -> certificate fails -> exact).
//   sigmoid monotone => column mins on RAW W, one sigmoid at the end.
//
// Fusion: 384 blocks. Blocks [0,128) = producers: pmin partials of W, then
// __threadfence (L2 writeback) + release-store MAGIC flag. Blocks [128,384)
// = consumers: local rowsums for 16 xs rows FIRST (overlaps producers), then
// acquire-spin on the 128 flags (buffer_inv -> no stale cross-XCD L2 reads,
// G16 pattern), fold pmin, certify, write. Deadlock-free: 384 blocks x 4
// waves = 1536 waves << device capacity -> all blocks co-resident regardless
// of dispatch order. MAGIC compare (not counting) is robust to any initial
// ws content (harness poisons 0xAA; 0xAAAAAAAA != MAGIC, 0 != MAGIC).
// ws: pmin[32][1024] f32 (128 KB) @0, flags[128] u32 @128KB.

constexpr int Bsz = 4096;
constexpr int IN  = 1024;
constexpr int OUT = 1024;
constexpr unsigned MAGIC = 0x13579BDFu;

// exact fp32 dot for uncertified outputs (rare; never on bench distribution)
__device__ __noinline__ float exact_out(const float* xs, const float* w,
                                        int brow, int j) {
    float s = 0.0f;
#pragma unroll 4
    for (int i = 0; i < IN; ++i)
        s += (1.0f - xs[(size_t)brow * IN + i]) *
             (1.0f / (1.0f + expf(-w[(size_t)i * OUT + j])));
    float v = 1.0f - s;
    return v > 0.0f ? v : 0.0f;
}

__global__ __launch_bounds__(256) void fuzzy_fused(const float* __restrict__ xs,
                                                   const float* __restrict__ w,
                                                   float* __restrict__ pmin,
                                                   unsigned* __restrict__ flags,
                                                   float* __restrict__ out) {
    const int t = threadIdx.x;

    if (blockIdx.x < 128) {
        // ---- producer: column-min partial over 32-row chunk of W ----
        const int ic = blockIdx.x >> 2;                 // [0,32)
        const int j  = (blockIdx.x & 3) * 256 + t;
        const float* base = w + (size_t)(ic * 32) * OUT + j;
        float m = 1e30f;
#pragma unroll
        for (int r = 0; r < 32; ++r) m = fminf(m, base[(size_t)r * OUT]);
        pmin[ic * OUT + j] = m;
        __threadfence();        // agent-scope release: drains + writes back L2
        __syncthreads();        // all threads' stores fenced before publish
        if (t == 0)
            __hip_atomic_store(&flags[blockIdx.x], MAGIC,
                               __ATOMIC_RELEASE, __HIP_MEMORY_SCOPE_AGENT);
        return;
    }

    // ---- consumer: 256 blocks, each = 16 b-rows x all 1024 j ----
    __shared__ float ps[16][16];   // rowsum partials
    __shared__ float pmx[16][16];  // row-max partials (validity)
    __shared__ float rs[16];
    const int cb  = blockIdx.x - 128;   // [0,256)
    const int r0  = cb * 16;
    const int row = t >> 4;             // [0,16)
    const int seg = t & 15;

    // local rowsum first — overlaps with producer blocks running elsewhere.
    // interleaved float4 reads: consecutive seg -> consecutive addresses.
    const float4* xb = (const float4*)(xs + (size_t)(r0 + row) * IN);
    float s = 0.0f, mx = -1e30f;
#pragma unroll
    for (int i = 0; i < 16; ++i) {
        float4 v = xb[i * 16 + seg];
        s += (1.0f - v.x) + (1.0f - v.y) + (1.0f - v.z) + (1.0f - v.w);
        mx = fmaxf(mx, fmaxf(fmaxf(v.x, v.y), fmaxf(v.z, v.w)));
    }
    ps[row][seg]  = s;
    pmx[row][seg] = mx;
    __syncthreads();
    if (t < 16) {
        float ss = 0.0f, mm = -1e30f;
#pragma unroll
        for (int k = 0; k < 16; ++k) {
            ss += ps[t][k];
            mm = fmaxf(mm, pmx[t][k]);
        }
        // xs > 1 invalidates the bound: poison row to NaN -> all certificates
        // fail -> exact fallback path.
        rs[t] = (mm <= 1.0f) ? ss : (0.0f / 0.0f);
    }

    // wait for producers: threads 0..127 each watch one flag (acquire ->
    // buffer_inv: stale per-XCD L2 lines for pmin are invalidated).
    if (t < 128) {
        while (__hip_atomic_load(&flags[t], __ATOMIC_ACQUIRE,
                                 __HIP_MEMORY_SCOPE_AGENT) != MAGIC) {}
    }
    __syncthreads();

    // fold pmin for this thread's 4 columns, one sigmoid per column
    const int j = t * 4;
    float4 m4 = make_float4(1e30f, 1e30f, 1e30f, 1e30f);
#pragma unroll
    for (int ic = 0; ic < 32; ++ic) {
        float4 p = *(const float4*)(pmin + ic * OUT + j);
        m4.x = fminf(m4.x, p.x); m4.y = fminf(m4.y, p.y);
        m4.z = fminf(m4.z, p.z); m4.w = fminf(m4.w, p.w);
    }
    float4 wm;
    wm.x = 1.0f / (1.0f + expf(-m4.x));
    wm.y = 1.0f / (1.0f + expf(-m4.y));
    wm.z = 1.0f / (1.0f + expf(-m4.z));
    wm.w = 1.0f / (1.0f + expf(-m4.w));

#pragma unroll 4
    for (int b = 0; b < 16; ++b) {
        const int brow = r0 + b;
        const float r = rs[b];
        float4 v = make_float4(0.0f, 0.0f, 0.0f, 0.0f);
        // certificate: r*wm > 1.01 => s >= 1 => out = 0 (margin >> fp32 error)
        bool c0 = r * wm.x > 1.01f, c1 = r * wm.y > 1.01f;
        bool c2 = r * wm.z > 1.01f, c3 = r * wm.w > 1.01f;
        if (!(c0 && c1 && c2 && c3)) {  // execz-skipped when all certify
            if (!c0) v.x = exact_out(xs, w, brow, j + 0);
            if (!c1) v.y = exact_out(xs, w, brow, j + 1);
            if (!c2) v.z = exact_out(xs, w, brow, j + 2);
            if (!c3) v.w = exact_out(xs, w, brow, j + 3);
        }
        *(float4*)(out + (size_t)brow * OUT + j) = v;
    }
}

extern "C" void kernel_launch(void* const* d_in, const int* in_sizes, int n_in,
                              void* d_out, int out_size, void* d_ws, size_t ws_size,
                              hipStream_t stream) {
    const float* xs = (const float*)d_in[0];   // [4096][1024]
    const float* wt = (const float*)d_in[1];   // [1024][1024]
    float* out = (float*)d_out;                // [4096][1024]

    float*    pmin  = (float*)d_ws;                        // 128 KB
    unsigned* flags = (unsigned*)((char*)d_ws + 32 * OUT * sizeof(float));

    fuzzy_fused<<<384, 256, 0, stream>>>(xs, wt, pmin, flags, out);
}

// Round 13
// 74.631 us; speedup vs baseline: 1.5055x; 1.5055x over previous
//
#include <hip/hip_runtime.h>
#include <math.h>

// FuzzyAND: out[b,j] = max(0, 1 - sum_i sigmoid(W)[i,j] * (1 - xs[b,i]))
// B=4096, IN=1024, OUT=1024, fp32 in/out.
//
// R13 = exact revert to R10 (measured best: 74.2 us). Certified-bound
// algorithm. With a_i = 1-xs[b,i] >= 0 and w_i = sigmoid(W[i,j]) in (0,1):
//     s[b,j] = sum_i a_i w_i  >=  (sum_i a_i) * min_i w_i = rowsum[b]*wmin[j]
// If rowsum[b]*wmin[j] > 1.01 (margin covers all fp32 eval error; rowsum~512,
// wmin~0.03 -> bound~16 here), then s >= 1 exactly and out = 0 -- certified.
// Outputs failing the certificate (incl. NaN / xs>1, which poison rowsum to
// NaN and fail the > test) are computed EXACTLY inline in fp32. Correct for
// all inputs; O(B*IN + IN*OUT + B*OUT) instead of O(B*IN*OUT) when the AND
// saturates (intrinsic to fan-in-1024 Lukasiewicz AND).
// sigmoid is monotone -> min_i sigmoid(W[i,j]) = sigmoid(min_i W[i,j]):
// column mins are taken on RAW weights, one sigmoid at the end.
//
// Post-mortems that justify this exact shape:
//   R11 (K1=pmin-only, K2=local rowsums, 512 blocks): 76.1 — fold redundancy
//       doubled, regressed.
//   R12 (single-kernel producer/consumer handshake): 112 (one replay 19.9ms)
//       — acquire-spin thrashed L2 (FETCH_SIZE 10-21 GB), G16 hazard.
// K1: rowsum[b] (+ xs<=1 validity, NaN-poisoned) and 32-way column-min
//     partials of W. K2: fold partials, certify, write (or exact-fallback).
// ws: rowsum[4096] f32 @0, pmin[32][1024] f32 @16KB. All ws bytes read by K2
// are written by K1 first (harness poisons ws with 0xAA every replay).

constexpr int Bsz = 4096;
constexpr int IN  = 1024;
constexpr int OUT = 1024;

// ---- K1: blocks [0,1024): rowsum of (1-xs), 1 wave per row.
//          blocks [1024,1152): column-min partials of W over 32-row chunks.
__global__ __launch_bounds__(256) void k1_stats(const float* __restrict__ xs,
                                                const float* __restrict__ w,
                                                float* __restrict__ rowsum,
                                                float* __restrict__ pmin) {
    if (blockIdx.x < 1024) {
        const int b    = blockIdx.x * 4 + (threadIdx.x >> 6);
        const int lane = threadIdx.x & 63;
        const float4* p = (const float4*)(xs + (size_t)b * IN);
        float s = 0.0f, xmax = -1e30f;
#pragma unroll
        for (int r = 0; r < 4; ++r) {
            float4 v = p[r * 64 + lane];
            s += (1.0f - v.x) + (1.0f - v.y) + (1.0f - v.z) + (1.0f - v.w);
            xmax = fmaxf(xmax, fmaxf(fmaxf(v.x, v.y), fmaxf(v.z, v.w)));
        }
#pragma unroll
        for (int off = 32; off; off >>= 1) {
            s += __shfl_xor(s, off);
            xmax = fmaxf(xmax, __shfl_xor(xmax, off));
        }
        if (lane == 0) {
            // xs > 1 would make a_i < 0, invalidating the bound: poison to NaN
            // so every certificate on this row fails -> exact fallback path.
            rowsum[b] = (xmax <= 1.0f) ? s : (0.0f / 0.0f);
        }
    } else {
        const int wb = blockIdx.x - 1024;
        const int ic = wb >> 2;                 // [0,32) 32-row chunk
        const int j  = (wb & 3) * 256 + threadIdx.x;
        const float* base = w + (size_t)(ic * 32) * OUT + j;
        float m = 1e30f;
#pragma unroll
        for (int r = 0; r < 32; ++r) m = fminf(m, base[(size_t)r * OUT]);
        pmin[ic * OUT + j] = m;
    }
}

// exact fp32 dot for uncertified outputs (rare; never on bench distribution)
__device__ __noinline__ float exact_out(const float* xs, const float* w,
                                        int brow, int j) {
    float s = 0.0f;
#pragma unroll 4
    for (int i = 0; i < IN; ++i)
        s += (1.0f - xs[(size_t)brow * IN + i]) *
             (1.0f / (1.0f + expf(-w[(size_t)i * OUT + j])));
    float v = 1.0f - s;
    return v > 0.0f ? v : 0.0f;
}

// ---- K2: 256 blocks x 256 threads; block = 16 b-rows x all 1024 j.
// Thread t owns columns j=4t..4t+3: folds 32 pmin partials (float4, coalesced),
// one sigmoid per column, then 16 certified float4 stores.
__global__ __launch_bounds__(256) void k2_write(const float* __restrict__ xs,
                                                const float* __restrict__ w,
                                                const float* __restrict__ rowsum,
                                                const float* __restrict__ pmin,
                                                float* __restrict__ out) {
    __shared__ float rs[16];
    const int bg = blockIdx.x;
    const int t  = threadIdx.x;
    const int j  = t * 4;

    float4 m = make_float4(1e30f, 1e30f, 1e30f, 1e30f);
#pragma unroll
    for (int ic = 0; ic < 32; ++ic) {
        float4 p = *(const float4*)(pmin + ic * OUT + j);
        m.x = fminf(m.x, p.x); m.y = fminf(m.y, p.y);
        m.z = fminf(m.z, p.z); m.w = fminf(m.w, p.w);
    }
    float4 wm;
    wm.x = 1.0f / (1.0f + expf(-m.x));
    wm.y = 1.0f / (1.0f + expf(-m.y));
    wm.z = 1.0f / (1.0f + expf(-m.z));
    wm.w = 1.0f / (1.0f + expf(-m.w));

    if (t < 16) rs[t] = rowsum[bg * 16 + t];
    __syncthreads();

#pragma unroll 4
    for (int b = 0; b < 16; ++b) {
        const int brow = bg * 16 + b;
        const float r = rs[b];
        float4 v = make_float4(0.0f, 0.0f, 0.0f, 0.0f);
        // certificate: r*wm > 1.01 (margin >> all fp32 eval error) => out = 0
        bool c0 = r * wm.x > 1.01f, c1 = r * wm.y > 1.01f;
        bool c2 = r * wm.z > 1.01f, c3 = r * wm.w > 1.01f;
        if (!(c0 && c1 && c2 && c3)) {   // wave-skipped via execz when all certify
            if (!c0) v.x = exact_out(xs, w, brow, j + 0);
            if (!c1) v.y = exact_out(xs, w, brow, j + 1);
            if (!c2) v.z = exact_out(xs, w, brow, j + 2);
            if (!c3) v.w = exact_out(xs, w, brow, j + 3);
        }
        *(float4*)(out + (size_t)brow * OUT + j) = v;
    }
}

extern "C" void kernel_launch(void* const* d_in, const int* in_sizes, int n_in,
                              void* d_out, int out_size, void* d_ws, size_t ws_size,
                              hipStream_t stream) {
    const float* xs = (const float*)d_in[0];   // [4096][1024]
    const float* wt = (const float*)d_in[1];   // [1024][1024]
    float* out = (float*)d_out;                // [4096][1024]

    float* rowsum = (float*)d_ws;              // 16 KB
    float* pmin   = rowsum + Bsz;              // 128 KB

    k1_stats<<<1024 + 128, 256, 0, stream>>>(xs, wt, rowsum, pmin);
    k2_write<<<256, 256, 0, stream>>>(xs, wt, rowsum, pmin, out);
}